// Round 1
// baseline (336.109 us; speedup 1.0000x reference)
//
#include <hip/hip_runtime.h>
#include <hip/hip_bf16.h>
#include <cstddef>

// ---------------------------------------------------------------------------
// MTCNN P-Net forward, NCHW in/out.
//   x[16,3,720,720] -> norm -> conv1(3->10,3x3)+PReLU -> maxpool2 (fp32 math)
//     -> pooled NHWC bf16 (padded 10->16 ch)
//     -> conv2(16->16,3x3) via MFMA 16x16x32 bf16 -> NHWC bf16
//     -> conv3(16->32,3x3)+PReLU via MFMA 32x32x16 bf16, fused heads
//   out = concat(reg[16,4,355,355], prob[16,2,355,355]) flat fp32
// ---------------------------------------------------------------------------

#define H1 718
#define PH 359   // pooled spatial
#define H2 357   // conv2 out spatial
#define H3 355   // conv3 out spatial

// workspace layout (float offsets)
#define W1R_OFF 0              // 270 fp32, pre-scaled by 1/128
#define B1R_OFF 288            // 10 fp32 (norm folded in)
#define AW2_OFF 320            // 2560 bf16 = 1280 fl: conv2 A-frags [step][lane][8]
#define BW3_OFF 1600           // 4608 bf16 = 2304 fl: conv3 B-frags [tap][lane][8]
#define P16_OFF 4096           // pooled NHWC bf16 [16,359,359,16] = 16496768 fl
#define C2H_OFF 16500864       // conv2 out NHWC bf16 [16,357,357,16] = 16313472 fl

typedef short bf16x8 __attribute__((ext_vector_type(8)));
typedef float f32x4  __attribute__((ext_vector_type(4)));
typedef float f32x16 __attribute__((ext_vector_type(16)));
typedef unsigned short ushort4v __attribute__((ext_vector_type(4)));

// ---------------------------------------------------------------------------
// Weight repack.
//  - conv1: fold (x-127.5)/128 into weights/bias (fp32).
//  - conv2: -> MFMA 16x16x32 A-frag order (A = weights, M=c_out), bf16:
//      k in [0,32) of step s: tap = 2s + (k>=16), ci = k&15 (real if ci<10,tap<9)
//      afrag[s][lane][j]: m=lane&15=c_out, k=(lane>>4)*8+j
//  - conv3: -> MFMA 32x32x16 B-frag order, bf16 (as R3, verified).
// ---------------------------------------------------------------------------
__global__ void repack_kernel(const float* __restrict__ w1, const float* __restrict__ b1,
                              const float* __restrict__ w2, const float* __restrict__ w3,
                              float* __restrict__ ws) {
    int t = threadIdx.x;
    const float S = 0.0078125f;
    for (int i = t; i < 270; i += blockDim.x) ws[W1R_OFF + i] = w1[i] * S;
    if (t < 10) {
        float s = 0.f;
        for (int i = 0; i < 27; i++) s += w1[t * 27 + i];
        ws[B1R_OFF + t] = b1[t] - 127.5f * S * s;
    }
    unsigned short* aw2 = (unsigned short*)(ws + AW2_OFF);
    for (int e = t; e < 2560; e += blockDim.x) {
        int s = e >> 9;              // K-step 0..4
        int rem = e & 511;
        int l = rem >> 3, j = rem & 7;
        int q = l >> 4, co = l & 15;
        int tap = 2 * s + (q >> 1);
        int ci  = ((q & 1) << 3) + j;
        float v = (tap < 9 && ci < 10) ? w2[co * 90 + ci * 9 + tap] : 0.f;
        __hip_bfloat16 h = __float2bfloat16(v);
        aw2[e] = *(unsigned short*)&h;
    }
    unsigned short* bw3 = (unsigned short*)(ws + BW3_OFF);
    for (int e = t; e < 4608; e += blockDim.x) {
        int tap = e >> 9;
        int rem = e & 511;
        int l = rem >> 3, j = rem & 7;
        int kh = tap / 3, kw = tap % 3;
        int co = l & 31, ci = ((l >> 5) << 3) + j;
        float v = w3[co * 144 + ci * 9 + kh * 3 + kw];
        __hip_bfloat16 h = __float2bfloat16(v);
        bw3[e] = *(unsigned short*)&h;
    }
}

// ---------------------------------------------------------------------------
// Stage 1: norm+conv1+PReLU+maxpool fused, fp32 math.
// v2: 2 pooled px per thread (register-blocked):
//   - window 4 rows x 6 cols per ci (float4+float2 loads, 16 B lane stride)
//   - 2160 FMA / thread, acc[10][2][4] with bias folded into init
//   - epilogue: max(prelu(s_i)) == max(prelu(max s), prelu(min s)) (exact for
//     any PReLU slope since prelu is piecewise monotone) -> no per-position
//     bias/prelu work
// Output NHWC bf16 padded to 16 ch (two 32 B stores per thread).
// grid: (3, 180, 16), block (64,2).
// ---------------------------------------------------------------------------
__global__ __launch_bounds__(128)
void conv1_pool_kernel(const float* __restrict__ x,
                       const float* __restrict__ ws,
                       const float* __restrict__ a1,
                       __hip_bfloat16* __restrict__ p16) {
    int pwp = blockIdx.x * 64 + threadIdx.x;   // pooled-px pair index
    int ph  = blockIdx.y * 2 + threadIdx.y;
    int n   = blockIdx.z;
    if (ph >= PH || 2 * pwp >= PH) return;
    bool tail = (2 * pwp + 1 >= PH);           // last pair: only px0 valid
    int iy = 2 * ph;
    int ix = 4 * pwp;
    // tail thread must not read cols 720..721; clamp the float2 load (its
    // values only feed the dead px1 accumulators)
    int t2off = tail ? 0 : 4;

    // bias folded into accumulator init
    float acc[10][2][4];
    #pragma unroll
    for (int c = 0; c < 10; c++) {
        float b = ws[B1R_OFF + c];
        #pragma unroll
        for (int r = 0; r < 2; r++)
            #pragma unroll
            for (int p = 0; p < 4; p++) acc[c][r][p] = b;
    }

    #pragma unroll
    for (int ci = 0; ci < 3; ci++) {
        const float* xp = x + (((size_t)(n * 3 + ci) * 720 + iy) * 720 + ix);
        float win[4][6];
        #pragma unroll
        for (int r = 0; r < 4; r++) {
            float4 v0 = *(const float4*)(xp + r * 720);
            float2 v1 = *(const float2*)(xp + r * 720 + t2off);
            win[r][0] = v0.x; win[r][1] = v0.y; win[r][2] = v0.z; win[r][3] = v0.w;
            win[r][4] = v1.x; win[r][5] = v1.y;
        }
        #pragma unroll
        for (int c = 0; c < 10; c++) {
            const float* wk = ws + W1R_OFF + c * 27 + ci * 9;
            #pragma unroll
            for (int kh = 0; kh < 3; kh++)
                #pragma unroll
                for (int kw = 0; kw < 3; kw++) {
                    float wv = wk[kh * 3 + kw];
                    #pragma unroll
                    for (int rr = 0; rr < 2; rr++)
                        #pragma unroll
                        for (int cc = 0; cc < 4; cc++)
                            acc[c][rr][cc] = fmaf(win[rr + kh][cc + kw], wv, acc[c][rr][cc]);
                }
        }
    }

    // epilogue: pooled = max(prelu(max4), prelu(min4)); bf16 pack, pad to 16ch
    __hip_bfloat16 o0[16], o1[16];
    #pragma unroll
    for (int c = 0; c < 10; c++) {
        float al = a1[c];
        // px0: cols 0,1
        float mx0 = fmaxf(fmaxf(acc[c][0][0], acc[c][0][1]),
                          fmaxf(acc[c][1][0], acc[c][1][1]));
        float mn0 = fminf(fminf(acc[c][0][0], acc[c][0][1]),
                          fminf(acc[c][1][0], acc[c][1][1]));
        float pa0 = mx0 >= 0.f ? mx0 : al * mx0;
        float pb0 = mn0 >= 0.f ? mn0 : al * mn0;
        o0[c] = __float2bfloat16(fmaxf(pa0, pb0));
        // px1: cols 2,3
        float mx1 = fmaxf(fmaxf(acc[c][0][2], acc[c][0][3]),
                          fmaxf(acc[c][1][2], acc[c][1][3]));
        float mn1 = fminf(fminf(acc[c][0][2], acc[c][0][3]),
                          fminf(acc[c][1][2], acc[c][1][3]));
        float pa1 = mx1 >= 0.f ? mx1 : al * mx1;
        float pb1 = mn1 >= 0.f ? mn1 : al * mn1;
        o1[c] = __float2bfloat16(fmaxf(pa1, pb1));
    }
    #pragma unroll
    for (int c = 10; c < 16; c++) { o0[c] = __float2bfloat16(0.f); o1[c] = __float2bfloat16(0.f); }

    float4* dst = (float4*)(p16 + (((size_t)n * PH + ph) * PH + 2 * pwp) * 16);
    dst[0] = ((float4*)o0)[0];
    dst[1] = ((float4*)o0)[1];
    if (!tail) {
        dst[2] = ((float4*)o1)[0];
        dst[3] = ((float4*)o1)[1];
    }
}

// ---------------------------------------------------------------------------
// Stage 2: conv2 3x3 (16pad->16) + bias + PReLU, MFMA 16x16x32 bf16.
// A = weights (M=16 c_out, register-resident), B = pixels (N=16 px) -> D has
// col=px, row=c_out, so the NHWC store is 512 B fully-coalesced per tile
// (lane writes px=(lane&15)'s ch-quad (lane>>4)*4 as one 8 B chunk).
// K=32 = 2 taps x 16ch(10 real); 9 taps -> 5 K-steps, last half zero-padded.
// Wave = 64 px of one output row (4 tiles), 20 MFMA, 18 x 16 B B-loads/lane.
// grid: (ceil(357/64)=6, ceil(357/4)=90, 16), block 256. No barriers.
// ---------------------------------------------------------------------------
__global__ __launch_bounds__(256)
void conv2_mfma_kernel(const __hip_bfloat16* __restrict__ p16,
                       const float* __restrict__ ws,
                       const float* __restrict__ b2,
                       const float* __restrict__ a2,
                       __hip_bfloat16* __restrict__ c2h) {
    int wv = threadIdx.x >> 6;
    int l  = threadIdx.x & 63;
    int oh  = blockIdx.y * 4 + wv;
    int ow0 = blockIdx.x * 64;
    int n   = blockIdx.z;
    if (oh >= H2) return;

    int pxl = l & 15;          // B col: px within tile
    int q   = l >> 4;
    int taph = q >> 1;         // which tap within K-step
    int choff = (q & 1) << 3;  // channel sub-chunk

    const bf16x8* aw = (const bf16x8*)(ws + AW2_OFF);
    bf16x8 afr[5];
    #pragma unroll
    for (int s = 0; s < 5; s++) afr[s] = aw[s * 64 + l];

    bf16x8 zf;
    #pragma unroll
    for (int j = 0; j < 8; j++) zf[j] = 0;

    f32x4 acc[4];
    #pragma unroll
    for (int t = 0; t < 4; t++)
        #pragma unroll
        for (int i = 0; i < 4; i++) acc[t][i] = 0.f;

    #pragma unroll
    for (int s = 0; s < 5; s++) {
        int tap = 2 * s + taph;
        bool real = (tap < 9);
        int kh = tap / 3, kw = tap - kh * 3;
        int ih = oh + kh; if (ih > PH - 1) ih = PH - 1;   // only pad-tap can exceed
        #pragma unroll
        for (int t = 0; t < 4; t++) {
            int iw = ow0 + t * 16 + pxl + kw; if (iw > PH - 1) iw = PH - 1;
            const bf16x8* bp = (const bf16x8*)(p16 + (((size_t)n * PH + ih) * PH + iw) * 16 + choff);
            bf16x8 b = real ? *bp : zf;
            acc[t] = __builtin_amdgcn_mfma_f32_16x16x32_bf16(afr[s], b, acc[t], 0, 0, 0);
        }
    }

    // epilogue: bias+PReLU; lane's elements are (c_out = q*4+r, px = pxl)
    float bb[4], aa[4];
    #pragma unroll
    for (int r = 0; r < 4; r++) { bb[r] = b2[q * 4 + r]; aa[r] = a2[q * 4 + r]; }

    #pragma unroll
    for (int t = 0; t < 4; t++) {
        int px = ow0 + t * 16 + pxl;
        if (px < H2) {
            ushort4v pk;
            #pragma unroll
            for (int r = 0; r < 4; r++) {
                float v = acc[t][r] + bb[r];
                v = v >= 0.f ? v : aa[r] * v;
                __hip_bfloat16 h = __float2bfloat16(v);
                pk[r] = *(unsigned short*)&h;
            }
            *(ushort4v*)(c2h + (((size_t)n * H2 + oh) * H2 + px) * 16 + q * 4) = pk;
        }
    }
}

// ---------------------------------------------------------------------------
// Stage 3: conv3 3x3 (16->32) + PReLU + heads, MFMA 32x32x16 bf16 (R3,
// verified). A = pixels, B = weights; heads via stride-33 LDS; softmax.
// grid: (12, 45, 16), block 256
// ---------------------------------------------------------------------------
__global__ __launch_bounds__(256, 1)
void conv3_heads_kernel(const __hip_bfloat16* __restrict__ c2h,
                        const float* __restrict__ ws,
                        const float* __restrict__ b3,
                        const float* __restrict__ a3,
                        const float* __restrict__ w41,
                        const float* __restrict__ b41,
                        const float* __restrict__ w42,
                        const float* __restrict__ b42,
                        float* __restrict__ out) {
    int wv = threadIdx.x >> 6;
    int l  = threadIdx.x & 63;
    int ow0 = blockIdx.x * 32;
    int oh0 = blockIdx.y * 8 + wv * 2;
    int n   = blockIdx.z;

    int m    = l & 31;
    int half = l >> 5;
    int choff = half << 3;

    const bf16x8* bw = (const bf16x8*)(ws + BW3_OFF);
    bf16x8 bfr[9];
    #pragma unroll
    for (int t = 0; t < 9; t++) bfr[t] = bw[t * 64 + l];

    f32x16 acc0, acc1;
    #pragma unroll
    for (int i = 0; i < 16; i++) { acc0[i] = 0.f; acc1[i] = 0.f; }

    #pragma unroll
    for (int kh = 0; kh < 3; kh++) {
        int ih0 = oh0 + kh;     if (ih0 > H2 - 1) ih0 = H2 - 1;
        int ih1 = oh0 + 1 + kh; if (ih1 > H2 - 1) ih1 = H2 - 1;
        #pragma unroll
        for (int kw = 0; kw < 3; kw++) {
            int iw = ow0 + m + kw; if (iw > H2 - 1) iw = H2 - 1;
            const bf16x8* a0p = (const bf16x8*)(c2h + ((((size_t)n * H2 + ih0) * H2 + iw) << 4) + choff);
            const bf16x8* a1p = (const bf16x8*)(c2h + ((((size_t)n * H2 + ih1) * H2 + iw) << 4) + choff);
            bf16x8 a0 = *a0p;
            bf16x8 a1 = *a1p;
            int tap = kh * 3 + kw;
            acc0 = __builtin_amdgcn_mfma_f32_32x32x16_bf16(a0, bfr[tap], acc0, 0, 0, 0);
            acc1 = __builtin_amdgcn_mfma_f32_32x32x16_bf16(a1, bfr[tap], acc1, 0, 0, 0);
        }
    }

    __shared__ float hbuf[4][64 * 33];
    float* hb = hbuf[wv];
    float bb = b3[m], aa = a3[m];
    #pragma unroll
    for (int t = 0; t < 2; t++) {
        #pragma unroll
        for (int r = 0; r < 16; r++) {
            int mprime = (r & 3) + ((r >> 2) << 3) + (half << 2);
            float v = (t ? acc1[r] : acc0[r]) + bb;
            v = v >= 0.f ? v : aa * v;
            hb[(t * 32 + mprime) * 33 + m] = v;
        }
    }
    __syncthreads();

    int poh = oh0 + (l >> 5);
    int pow_ = ow0 + (l & 31);
    float h[32];
    #pragma unroll
    for (int c = 0; c < 32; c++) h[c] = hb[l * 33 + c];

    float l0 = b41[0], l1 = b41[1];
    float r0 = b42[0], r1 = b42[1], r2 = b42[2], r3 = b42[3];
    #pragma unroll
    for (int c = 0; c < 32; c++) {
        float hv = h[c];
        l0 = fmaf(hv, w41[c],      l0);
        l1 = fmaf(hv, w41[32 + c], l1);
        r0 = fmaf(hv, w42[c],      r0);
        r1 = fmaf(hv, w42[32 + c], r1);
        r2 = fmaf(hv, w42[64 + c], r2);
        r3 = fmaf(hv, w42[96 + c], r3);
    }
    float mx  = fmaxf(l0, l1);
    float e0 = __expf(l0 - mx), e1 = __expf(l1 - mx);
    float inv = 1.0f / (e0 + e1);

    if (poh < H3 && pow_ < H3) {
        const size_t sp = (size_t)H3 * H3;
        size_t pos = (size_t)poh * H3 + pow_;
        float* reg  = out;
        float* prob = out + (size_t)16 * 4 * sp;
        reg[((size_t)(n * 4 + 0)) * sp + pos] = r0;
        reg[((size_t)(n * 4 + 1)) * sp + pos] = r1;
        reg[((size_t)(n * 4 + 2)) * sp + pos] = r2;
        reg[((size_t)(n * 4 + 3)) * sp + pos] = r3;
        prob[((size_t)(n * 2 + 0)) * sp + pos] = e0 * inv;
        prob[((size_t)(n * 2 + 1)) * sp + pos] = e1 * inv;
    }
}

extern "C" void kernel_launch(void* const* d_in, const int* in_sizes, int n_in,
                              void* d_out, int out_size, void* d_ws, size_t ws_size,
                              hipStream_t stream) {
    const float* x   = (const float*)d_in[0];
    const float* w1  = (const float*)d_in[1];
    const float* b1  = (const float*)d_in[2];
    const float* a1  = (const float*)d_in[3];
    const float* w2  = (const float*)d_in[4];
    const float* b2  = (const float*)d_in[5];
    const float* a2  = (const float*)d_in[6];
    const float* w3  = (const float*)d_in[7];
    const float* b3  = (const float*)d_in[8];
    const float* a3  = (const float*)d_in[9];
    const float* w41 = (const float*)d_in[10];
    const float* b41 = (const float*)d_in[11];
    const float* w42 = (const float*)d_in[12];
    const float* b42 = (const float*)d_in[13];
    float* out = (float*)d_out;
    float* ws  = (float*)d_ws;

    __hip_bfloat16* p16 = (__hip_bfloat16*)(ws + P16_OFF);
    __hip_bfloat16* c2h = (__hip_bfloat16*)(ws + C2H_OFF);

    repack_kernel<<<1, 256, 0, stream>>>(w1, b1, w2, w3, ws);

    {
        // 2 pooled px per thread: 180 pair-columns, 2 rows per block
        dim3 grid(3, (PH + 1) / 2, 16);
        dim3 block(64, 2);
        conv1_pool_kernel<<<grid, block, 0, stream>>>(x, ws, a1, p16);
    }
    {
        dim3 grid((H2 + 63) / 64, (H2 + 3) / 4, 16);
        conv2_mfma_kernel<<<grid, 256, 0, stream>>>(p16, ws, b2, a2, c2h);
    }
    {
        dim3 grid((H3 + 31) / 32, (H3 + 7) / 8, 16);
        conv3_heads_kernel<<<grid, 256, 0, stream>>>(c2h, ws, b3, a3,
                                                     w41, b41, w42, b42, out);
    }
}

// Round 2
// 335.673 us; speedup vs baseline: 1.0013x; 1.0013x over previous
//
#include <hip/hip_runtime.h>
#include <hip/hip_bf16.h>
#include <cstddef>

// ---------------------------------------------------------------------------
// MTCNN P-Net forward, NCHW in/out.
//   x[16,3,720,720] -> norm -> conv1(3->10,3x3)+PReLU -> maxpool2 (fp32 math)
//     -> pooled NHWC bf16 (padded 10->16 ch)
//     -> conv2(16->16,3x3) via MFMA 16x16x32 bf16 -> NHWC bf16
//     -> conv3(16->32,3x3)+PReLU via MFMA 32x32x16 bf16, fused heads
//   out = concat(reg[16,4,355,355], prob[16,2,355,355]) flat fp32
// ---------------------------------------------------------------------------

#define H1 718
#define PH 359   // pooled spatial
#define H2 357   // conv2 out spatial
#define H3 355   // conv3 out spatial

// workspace layout (float offsets)
#define W1R_OFF 0              // 270 fp32, pre-scaled by 1/128
#define B1R_OFF 288            // 10 fp32 (norm folded in)
#define AW2_OFF 320            // 2560 bf16 = 1280 fl: conv2 A-frags [step][lane][8]
#define BW3_OFF 1600           // 4608 bf16 = 2304 fl: conv3 B-frags [tap][lane][8]
#define P16_OFF 4096           // pooled NHWC bf16 [16,359,359,16] = 16496768 fl
#define C2H_OFF 16500864       // conv2 out NHWC bf16 [16,357,357,16] = 16313472 fl

typedef short bf16x8 __attribute__((ext_vector_type(8)));
typedef float f32x4  __attribute__((ext_vector_type(4)));
typedef float f32x16 __attribute__((ext_vector_type(16)));
typedef unsigned short ushort4v __attribute__((ext_vector_type(4)));

// ---------------------------------------------------------------------------
// Weight repack.
//  - conv1: fold (x-127.5)/128 into weights/bias (fp32).
//  - conv2: -> MFMA 16x16x32 A-frag order (A = weights, M=c_out), bf16:
//      k in [0,32) of step s: tap = 2s + (k>=16), ci = k&15 (real if ci<10,tap<9)
//      afrag[s][lane][j]: m=lane&15=c_out, k=(lane>>4)*8+j
//  - conv3: -> MFMA 32x32x16 B-frag order, bf16 (as R3, verified).
// ---------------------------------------------------------------------------
__global__ void repack_kernel(const float* __restrict__ w1, const float* __restrict__ b1,
                              const float* __restrict__ w2, const float* __restrict__ w3,
                              float* __restrict__ ws) {
    int t = threadIdx.x;
    const float S = 0.0078125f;
    for (int i = t; i < 270; i += blockDim.x) ws[W1R_OFF + i] = w1[i] * S;
    if (t < 10) {
        float s = 0.f;
        for (int i = 0; i < 27; i++) s += w1[t * 27 + i];
        ws[B1R_OFF + t] = b1[t] - 127.5f * S * s;
    }
    unsigned short* aw2 = (unsigned short*)(ws + AW2_OFF);
    for (int e = t; e < 2560; e += blockDim.x) {
        int s = e >> 9;              // K-step 0..4
        int rem = e & 511;
        int l = rem >> 3, j = rem & 7;
        int q = l >> 4, co = l & 15;
        int tap = 2 * s + (q >> 1);
        int ci  = ((q & 1) << 3) + j;
        float v = (tap < 9 && ci < 10) ? w2[co * 90 + ci * 9 + tap] : 0.f;
        __hip_bfloat16 h = __float2bfloat16(v);
        aw2[e] = *(unsigned short*)&h;
    }
    unsigned short* bw3 = (unsigned short*)(ws + BW3_OFF);
    for (int e = t; e < 4608; e += blockDim.x) {
        int tap = e >> 9;
        int rem = e & 511;
        int l = rem >> 3, j = rem & 7;
        int kh = tap / 3, kw = tap % 3;
        int co = l & 31, ci = ((l >> 5) << 3) + j;
        float v = w3[co * 144 + ci * 9 + kh * 3 + kw];
        __hip_bfloat16 h = __float2bfloat16(v);
        bw3[e] = *(unsigned short*)&h;
    }
}

// ---------------------------------------------------------------------------
// Stage 1: norm+conv1+PReLU+maxpool fused, fp32 math.
// v3: 2 pooled px per thread, CHANNEL-SPLIT into two groups of 5 to keep the
// live register set at the R0-proven size (no scratch spill — R1 post-mortem:
// acc[10][2][4]=80 live spilled, +62 MB scratch traffic):
//   - per group: acc[5][2][4]=40 live + win[4][6]=24, ~80 peak live
//   - window reloaded per group; block working set ~18.6 KB -> L1 hits,
//     HBM FETCH unchanged
//   - bias folded into acc init
//   - epilogue: max(prelu(s_i)) == max(prelu(max s), prelu(min s)) (exact for
//     any PReLU slope since prelu is piecewise monotone)
// Output NHWC bf16 padded to 16 ch (two/four 16 B stores per thread).
// grid: (3, 180, 16), block (64,2).
// ---------------------------------------------------------------------------
__global__ __launch_bounds__(128)
void conv1_pool_kernel(const float* __restrict__ x,
                       const float* __restrict__ ws,
                       const float* __restrict__ a1,
                       __hip_bfloat16* __restrict__ p16) {
    int pwp = blockIdx.x * 64 + threadIdx.x;   // pooled-px pair index
    int ph  = blockIdx.y * 2 + threadIdx.y;
    int n   = blockIdx.z;
    if (ph >= PH || 2 * pwp >= PH) return;
    bool tail = (2 * pwp + 1 >= PH);           // last pair: only px0 valid
    int iy = 2 * ph;
    int ix = 4 * pwp;
    // tail thread must not read cols 720..721; clamp the float2 load (its
    // values only feed the dead px1 accumulators)
    int t2off = tail ? 0 : 4;

    unsigned short o0u[16], o1u[16];

    #pragma unroll
    for (int g = 0; g < 2; g++) {
        // bias folded into accumulator init
        float acc[5][2][4];
        #pragma unroll
        for (int c = 0; c < 5; c++) {
            float b = ws[B1R_OFF + g * 5 + c];
            #pragma unroll
            for (int r = 0; r < 2; r++)
                #pragma unroll
                for (int p = 0; p < 4; p++) acc[c][r][p] = b;
        }

        #pragma unroll
        for (int ci = 0; ci < 3; ci++) {
            const float* xp = x + (((size_t)(n * 3 + ci) * 720 + iy) * 720 + ix);
            float win[4][6];
            #pragma unroll
            for (int r = 0; r < 4; r++) {
                float4 v0 = *(const float4*)(xp + r * 720);
                float2 v1 = *(const float2*)(xp + r * 720 + t2off);
                win[r][0] = v0.x; win[r][1] = v0.y; win[r][2] = v0.z; win[r][3] = v0.w;
                win[r][4] = v1.x; win[r][5] = v1.y;
            }
            #pragma unroll
            for (int c = 0; c < 5; c++) {
                const float* wk = ws + W1R_OFF + (g * 5 + c) * 27 + ci * 9;
                #pragma unroll
                for (int kh = 0; kh < 3; kh++)
                    #pragma unroll
                    for (int kw = 0; kw < 3; kw++) {
                        float wv = wk[kh * 3 + kw];
                        #pragma unroll
                        for (int rr = 0; rr < 2; rr++)
                            #pragma unroll
                            for (int cc = 0; cc < 4; cc++)
                                acc[c][rr][cc] = fmaf(win[rr + kh][cc + kw], wv, acc[c][rr][cc]);
                    }
            }
        }

        // epilogue for this channel group:
        // pooled = max(prelu(max4), prelu(min4)); bf16 pack
        #pragma unroll
        for (int c = 0; c < 5; c++) {
            int cc = g * 5 + c;
            float al = a1[cc];
            // px0: cols 0,1
            float mx0 = fmaxf(fmaxf(acc[c][0][0], acc[c][0][1]),
                              fmaxf(acc[c][1][0], acc[c][1][1]));
            float mn0 = fminf(fminf(acc[c][0][0], acc[c][0][1]),
                              fminf(acc[c][1][0], acc[c][1][1]));
            float pa0 = mx0 >= 0.f ? mx0 : al * mx0;
            float pb0 = mn0 >= 0.f ? mn0 : al * mn0;
            __hip_bfloat16 h0 = __float2bfloat16(fmaxf(pa0, pb0));
            o0u[cc] = *(unsigned short*)&h0;
            // px1: cols 2,3
            float mx1 = fmaxf(fmaxf(acc[c][0][2], acc[c][0][3]),
                              fmaxf(acc[c][1][2], acc[c][1][3]));
            float mn1 = fminf(fminf(acc[c][0][2], acc[c][0][3]),
                              fminf(acc[c][1][2], acc[c][1][3]));
            float pa1 = mx1 >= 0.f ? mx1 : al * mx1;
            float pb1 = mn1 >= 0.f ? mn1 : al * mn1;
            __hip_bfloat16 h1 = __float2bfloat16(fmaxf(pa1, pb1));
            o1u[cc] = *(unsigned short*)&h1;
        }
    }

    #pragma unroll
    for (int c = 10; c < 16; c++) { o0u[c] = 0; o1u[c] = 0; }

    float4* dst = (float4*)(p16 + (((size_t)n * PH + ph) * PH + 2 * pwp) * 16);
    dst[0] = ((float4*)o0u)[0];
    dst[1] = ((float4*)o0u)[1];
    if (!tail) {
        dst[2] = ((float4*)o1u)[0];
        dst[3] = ((float4*)o1u)[1];
    }
}

// ---------------------------------------------------------------------------
// Stage 2: conv2 3x3 (16pad->16) + bias + PReLU, MFMA 16x16x32 bf16.
// A = weights (M=16 c_out, register-resident), B = pixels (N=16 px) -> D has
// col=px, row=c_out, so the NHWC store is 512 B fully-coalesced per tile
// (lane writes px=(lane&15)'s ch-quad (lane>>4)*4 as one 8 B chunk).
// K=32 = 2 taps x 16ch(10 real); 9 taps -> 5 K-steps, last half zero-padded.
// Wave = 64 px of one output row (4 tiles), 20 MFMA, 18 x 16 B B-loads/lane.
// grid: (ceil(357/64)=6, ceil(357/4)=90, 16), block 256. No barriers.
// ---------------------------------------------------------------------------
__global__ __launch_bounds__(256)
void conv2_mfma_kernel(const __hip_bfloat16* __restrict__ p16,
                       const float* __restrict__ ws,
                       const float* __restrict__ b2,
                       const float* __restrict__ a2,
                       __hip_bfloat16* __restrict__ c2h) {
    int wv = threadIdx.x >> 6;
    int l  = threadIdx.x & 63;
    int oh  = blockIdx.y * 4 + wv;
    int ow0 = blockIdx.x * 64;
    int n   = blockIdx.z;
    if (oh >= H2) return;

    int pxl = l & 15;          // B col: px within tile
    int q   = l >> 4;
    int taph = q >> 1;         // which tap within K-step
    int choff = (q & 1) << 3;  // channel sub-chunk

    const bf16x8* aw = (const bf16x8*)(ws + AW2_OFF);
    bf16x8 afr[5];
    #pragma unroll
    for (int s = 0; s < 5; s++) afr[s] = aw[s * 64 + l];

    bf16x8 zf;
    #pragma unroll
    for (int j = 0; j < 8; j++) zf[j] = 0;

    f32x4 acc[4];
    #pragma unroll
    for (int t = 0; t < 4; t++)
        #pragma unroll
        for (int i = 0; i < 4; i++) acc[t][i] = 0.f;

    #pragma unroll
    for (int s = 0; s < 5; s++) {
        int tap = 2 * s + taph;
        bool real = (tap < 9);
        int kh = tap / 3, kw = tap - kh * 3;
        int ih = oh + kh; if (ih > PH - 1) ih = PH - 1;   // only pad-tap can exceed
        #pragma unroll
        for (int t = 0; t < 4; t++) {
            int iw = ow0 + t * 16 + pxl + kw; if (iw > PH - 1) iw = PH - 1;
            const bf16x8* bp = (const bf16x8*)(p16 + (((size_t)n * PH + ih) * PH + iw) * 16 + choff);
            bf16x8 b = real ? *bp : zf;
            acc[t] = __builtin_amdgcn_mfma_f32_16x16x32_bf16(afr[s], b, acc[t], 0, 0, 0);
        }
    }

    // epilogue: bias+PReLU; lane's elements are (c_out = q*4+r, px = pxl)
    float bb[4], aa[4];
    #pragma unroll
    for (int r = 0; r < 4; r++) { bb[r] = b2[q * 4 + r]; aa[r] = a2[q * 4 + r]; }

    #pragma unroll
    for (int t = 0; t < 4; t++) {
        int px = ow0 + t * 16 + pxl;
        if (px < H2) {
            ushort4v pk;
            #pragma unroll
            for (int r = 0; r < 4; r++) {
                float v = acc[t][r] + bb[r];
                v = v >= 0.f ? v : aa[r] * v;
                __hip_bfloat16 h = __float2bfloat16(v);
                pk[r] = *(unsigned short*)&h;
            }
            *(ushort4v*)(c2h + (((size_t)n * H2 + oh) * H2 + px) * 16 + q * 4) = pk;
        }
    }
}

// ---------------------------------------------------------------------------
// Stage 3: conv3 3x3 (16->32) + PReLU + heads, MFMA 32x32x16 bf16 (R3,
// verified). A = pixels, B = weights; heads via stride-33 LDS; softmax.
// grid: (12, 45, 16), block 256
// ---------------------------------------------------------------------------
__global__ __launch_bounds__(256, 1)
void conv3_heads_kernel(const __hip_bfloat16* __restrict__ c2h,
                        const float* __restrict__ ws,
                        const float* __restrict__ b3,
                        const float* __restrict__ a3,
                        const float* __restrict__ w41,
                        const float* __restrict__ b41,
                        const float* __restrict__ w42,
                        const float* __restrict__ b42,
                        float* __restrict__ out) {
    int wv = threadIdx.x >> 6;
    int l  = threadIdx.x & 63;
    int ow0 = blockIdx.x * 32;
    int oh0 = blockIdx.y * 8 + wv * 2;
    int n   = blockIdx.z;

    int m    = l & 31;
    int half = l >> 5;
    int choff = half << 3;

    const bf16x8* bw = (const bf16x8*)(ws + BW3_OFF);
    bf16x8 bfr[9];
    #pragma unroll
    for (int t = 0; t < 9; t++) bfr[t] = bw[t * 64 + l];

    f32x16 acc0, acc1;
    #pragma unroll
    for (int i = 0; i < 16; i++) { acc0[i] = 0.f; acc1[i] = 0.f; }

    #pragma unroll
    for (int kh = 0; kh < 3; kh++) {
        int ih0 = oh0 + kh;     if (ih0 > H2 - 1) ih0 = H2 - 1;
        int ih1 = oh0 + 1 + kh; if (ih1 > H2 - 1) ih1 = H2 - 1;
        #pragma unroll
        for (int kw = 0; kw < 3; kw++) {
            int iw = ow0 + m + kw; if (iw > H2 - 1) iw = H2 - 1;
            const bf16x8* a0p = (const bf16x8*)(c2h + ((((size_t)n * H2 + ih0) * H2 + iw) << 4) + choff);
            const bf16x8* a1p = (const bf16x8*)(c2h + ((((size_t)n * H2 + ih1) * H2 + iw) << 4) + choff);
            bf16x8 a0 = *a0p;
            bf16x8 a1 = *a1p;
            int tap = kh * 3 + kw;
            acc0 = __builtin_amdgcn_mfma_f32_32x32x16_bf16(a0, bfr[tap], acc0, 0, 0, 0);
            acc1 = __builtin_amdgcn_mfma_f32_32x32x16_bf16(a1, bfr[tap], acc1, 0, 0, 0);
        }
    }

    __shared__ float hbuf[4][64 * 33];
    float* hb = hbuf[wv];
    float bb = b3[m], aa = a3[m];
    #pragma unroll
    for (int t = 0; t < 2; t++) {
        #pragma unroll
        for (int r = 0; r < 16; r++) {
            int mprime = (r & 3) + ((r >> 2) << 3) + (half << 2);
            float v = (t ? acc1[r] : acc0[r]) + bb;
            v = v >= 0.f ? v : aa * v;
            hb[(t * 32 + mprime) * 33 + m] = v;
        }
    }
    __syncthreads();

    int poh = oh0 + (l >> 5);
    int pow_ = ow0 + (l & 31);
    float h[32];
    #pragma unroll
    for (int c = 0; c < 32; c++) h[c] = hb[l * 33 + c];

    float l0 = b41[0], l1 = b41[1];
    float r0 = b42[0], r1 = b42[1], r2 = b42[2], r3 = b42[3];
    #pragma unroll
    for (int c = 0; c < 32; c++) {
        float hv = h[c];
        l0 = fmaf(hv, w41[c],      l0);
        l1 = fmaf(hv, w41[32 + c], l1);
        r0 = fmaf(hv, w42[c],      r0);
        r1 = fmaf(hv, w42[32 + c], r1);
        r2 = fmaf(hv, w42[64 + c], r2);
        r3 = fmaf(hv, w42[96 + c], r3);
    }
    float mx  = fmaxf(l0, l1);
    float e0 = __expf(l0 - mx), e1 = __expf(l1 - mx);
    float inv = 1.0f / (e0 + e1);

    if (poh < H3 && pow_ < H3) {
        const size_t sp = (size_t)H3 * H3;
        size_t pos = (size_t)poh * H3 + pow_;
        float* reg  = out;
        float* prob = out + (size_t)16 * 4 * sp;
        reg[((size_t)(n * 4 + 0)) * sp + pos] = r0;
        reg[((size_t)(n * 4 + 1)) * sp + pos] = r1;
        reg[((size_t)(n * 4 + 2)) * sp + pos] = r2;
        reg[((size_t)(n * 4 + 3)) * sp + pos] = r3;
        prob[((size_t)(n * 2 + 0)) * sp + pos] = e0 * inv;
        prob[((size_t)(n * 2 + 1)) * sp + pos] = e1 * inv;
    }
}

extern "C" void kernel_launch(void* const* d_in, const int* in_sizes, int n_in,
                              void* d_out, int out_size, void* d_ws, size_t ws_size,
                              hipStream_t stream) {
    const float* x   = (const float*)d_in[0];
    const float* w1  = (const float*)d_in[1];
    const float* b1  = (const float*)d_in[2];
    const float* a1  = (const float*)d_in[3];
    const float* w2  = (const float*)d_in[4];
    const float* b2  = (const float*)d_in[5];
    const float* a2  = (const float*)d_in[6];
    const float* w3  = (const float*)d_in[7];
    const float* b3  = (const float*)d_in[8];
    const float* a3  = (const float*)d_in[9];
    const float* w41 = (const float*)d_in[10];
    const float* b41 = (const float*)d_in[11];
    const float* w42 = (const float*)d_in[12];
    const float* b42 = (const float*)d_in[13];
    float* out = (float*)d_out;
    float* ws  = (float*)d_ws;

    __hip_bfloat16* p16 = (__hip_bfloat16*)(ws + P16_OFF);
    __hip_bfloat16* c2h = (__hip_bfloat16*)(ws + C2H_OFF);

    repack_kernel<<<1, 256, 0, stream>>>(w1, b1, w2, w3, ws);

    {
        // 2 pooled px per thread: 180 pair-columns, 2 rows per block
        dim3 grid(3, (PH + 1) / 2, 16);
        dim3 block(64, 2);
        conv1_pool_kernel<<<grid, block, 0, stream>>>(x, ws, a1, p16);
    }
    {
        dim3 grid((H2 + 63) / 64, (H2 + 3) / 4, 16);
        conv2_mfma_kernel<<<grid, 256, 0, stream>>>(p16, ws, b2, a2, c2h);
    }
    {
        dim3 grid((H3 + 31) / 32, (H3 + 7) / 8, 16);
        conv3_heads_kernel<<<grid, 256, 0, stream>>>(c2h, ws, b3, a3,
                                                     w41, b41, w42, b42, out);
    }
}